// Round 4
// baseline (58.571 us; speedup 1.0000x reference)
//
#include <hip/hip_runtime.h>
#include <hip/hip_cooperative_groups.h>

namespace cg = cooperative_groups;

#define N 768
#define H 128
#define NM1 767
#define LDSW 132   // stride mod 32 = 4 -> consecutive rows shift 4 banks: conflict-free b128

union Smem {
  struct {                      // phase A
    float zsh[12][H];           // 12 z rows (reads are wave-uniform -> no pad needed)
    float w1s[64][LDSW];        // 64 output-cols' weight rows (one half-section)
  } a;
  struct {                      // phase B
    float ush[48 * LDSW];
    float vsh[48 * LDSW];
  } b;
};

__global__ __launch_bounds__(256) void fused_kernel(
    const float* __restrict__ z, const float* __restrict__ W1,
    const float* __restrict__ b1, const float* __restrict__ w2,
    const float* __restrict__ b2, float* __restrict__ U,
    float* __restrict__ Vb, float* __restrict__ out) {
  __shared__ Smem sm;
  const int t = threadIdx.x;
  const int blk = blockIdx.x;

  // ---------------- Phase A: U = z@W1a^T ; Vb = z@W1b^T + b1 ----------------
  {
    const int rg = blk >> 2;          // rows [12rg, 12rg+12)
    const int cg = blk & 3;           // out-col group: cols [64cg, 64cg+64)
    const int half = cg >> 1;         // 0 -> U, 1 -> Vb
    const int kbase = (cg & 1) * 64;
#pragma unroll
    for (int l = t; l < 12 * 32; l += 256) {       // stage z rows (6 KB)
      const int r = l >> 5, mq = l & 31;
      *(float4*)&sm.a.zsh[r][4 * mq] =
          ((const float4*)(z + (size_t)(12 * rg + r) * H))[mq];
    }
#pragma unroll
    for (int l = t; l < 64 * 32; l += 256) {       // stage W1 section (32 KB)
      const int cc = l >> 5, mq = l & 31;
      *(float4*)&sm.a.w1s[cc][4 * mq] =
          ((const float4*)(W1 + (size_t)(kbase + cc) * (2 * H) + half * H))[mq];
    }
    __syncthreads();
    const int cc = t & 63;            // per-lane col
    const int rslot = t >> 6;         // wave-uniform row slot (3 rows each)
    float acc0 = 0.f, acc1 = 0.f, acc2 = 0.f;
#pragma unroll 8
    for (int m = 0; m < H; m += 4) {
      const float4 w  = *(const float4*)&sm.a.w1s[cc][m];
      const float4 z0 = *(const float4*)&sm.a.zsh[3 * rslot + 0][m];
      const float4 z1 = *(const float4*)&sm.a.zsh[3 * rslot + 1][m];
      const float4 z2 = *(const float4*)&sm.a.zsh[3 * rslot + 2][m];
      acc0 = fmaf(w.x, z0.x, acc0); acc0 = fmaf(w.y, z0.y, acc0);
      acc0 = fmaf(w.z, z0.z, acc0); acc0 = fmaf(w.w, z0.w, acc0);
      acc1 = fmaf(w.x, z1.x, acc1); acc1 = fmaf(w.y, z1.y, acc1);
      acc1 = fmaf(w.z, z1.z, acc1); acc1 = fmaf(w.w, z1.w, acc1);
      acc2 = fmaf(w.x, z2.x, acc2); acc2 = fmaf(w.y, z2.y, acc2);
      acc2 = fmaf(w.z, z2.z, acc2); acc2 = fmaf(w.w, z2.w, acc2);
    }
    const int k = kbase + cc;
    const float bias = half ? b1[k] : 0.f;
    float* dst = half ? Vb : U;
    const int R = 12 * rg + 3 * rslot;
    dst[(size_t)(R + 0) * H + k] = acc0 + bias;
    dst[(size_t)(R + 1) * H + k] = acc1 + bias;
    dst[(size_t)(R + 2) * H + k] = acc2 + bias;
  }

  cg::this_grid().sync();   // device-scope fence + grid barrier: U/Vb visible to all XCDs

  // ---------------- Phase B: out[i,j] = sum_k relu(U[i,k]+Vb[j,k])*w2[k] + b2 ----------------
  {
    const int bi = (blk >> 4) * 48;
    const int bj = (blk & 15) * 48;
#pragma unroll
    for (int l = t; l < 48 * 32; l += 256) {
      const int r = l >> 5, c4 = l & 31;
      *(float4*)&sm.b.ush[r * LDSW + c4 * 4] = ((const float4*)(U  + (size_t)(bi + r) * H))[c4];
      *(float4*)&sm.b.vsh[r * LDSW + c4 * 4] = ((const float4*)(Vb + (size_t)(bj + r) * H))[c4];
    }
    __syncthreads();
    const int tx = t & 15, ty = t >> 4;
    float acc[3][3] = {};
#pragma unroll 8
    for (int k = 0; k < H; k += 4) {
      const float4 w = *(const float4*)(w2 + k);   // uniform -> scalar load
      float4 uu[3], vv[3];
#pragma unroll
      for (int r = 0; r < 3; ++r) uu[r] = *(const float4*)&sm.b.ush[(ty + 16 * r) * LDSW + k];
#pragma unroll
      for (int r = 0; r < 3; ++r) vv[r] = *(const float4*)&sm.b.vsh[(tx + 16 * r) * LDSW + k];
#pragma unroll
      for (int a = 0; a < 3; ++a)
#pragma unroll
        for (int b = 0; b < 3; ++b) {
          acc[a][b] = fmaf(fmaxf(uu[a].x + vv[b].x, 0.f), w.x, acc[a][b]);
          acc[a][b] = fmaf(fmaxf(uu[a].y + vv[b].y, 0.f), w.y, acc[a][b]);
          acc[a][b] = fmaf(fmaxf(uu[a].z + vv[b].z, 0.f), w.z, acc[a][b]);
          acc[a][b] = fmaf(fmaxf(uu[a].w + vv[b].w, 0.f), w.w, acc[a][b]);
        }
    }
    const float bb = b2[0];
#pragma unroll
    for (int a = 0; a < 3; ++a) {
      const int i = bi + ty + 16 * a;
#pragma unroll
      for (int b = 0; b < 3; ++b) {
        const int j = bj + tx + 16 * b;
        if (i != j) out[(size_t)i * NM1 + j - (j > i ? 1 : 0)] = acc[a][b] + bb;
      }
    }
  }
}

extern "C" void kernel_launch(void* const* d_in, const int* in_sizes, int n_in,
                              void* d_out, int out_size, void* d_ws, size_t ws_size,
                              hipStream_t stream) {
  const float* z  = (const float*)d_in[0];
  const float* W1 = (const float*)d_in[1];
  const float* b1 = (const float*)d_in[2];
  const float* W2 = (const float*)d_in[3];
  const float* b2 = (const float*)d_in[4];
  float* U  = (float*)d_ws;
  float* Vb = U + N * H;
  float* out = (float*)d_out;
  void* args[] = {(void*)&z, (void*)&W1, (void*)&b1, (void*)&W2,
                  (void*)&b2, (void*)&U, (void*)&Vb, (void*)&out};
  hipLaunchCooperativeKernel((const void*)fused_kernel, dim3(256), dim3(256),
                             args, 0, stream);
}

// Round 5
// 28.654 us; speedup vs baseline: 2.0441x; 2.0441x over previous
//
#include <hip/hip_runtime.h>

#define N 768
#define H 128
#define NM1 767

// ---------------- p0: W1T[m][k] = W1[k][m]   (W1:[128][256] -> W1T:[256][128]) ----------------
__global__ __launch_bounds__(256) void p0_transpose(const float* __restrict__ W1,
                                                    float* __restrict__ W1T) {
  const int g = blockIdx.x * 256 + threadIdx.x;   // 8192 float4 ids
  const float4 v = ((const float4*)W1)[g];
  const int k = g >> 6;            // W1 row (0..127)
  const int m = (g & 63) << 2;     // starting column
  W1T[(size_t)(m + 0) * H + k] = v.x;
  W1T[(size_t)(m + 1) * H + k] = v.y;
  W1T[(size_t)(m + 2) * H + k] = v.z;
  W1T[(size_t)(m + 3) * H + k] = v.w;
}

// ---------------- p1: U = z@W1a^T ; Vb = z@W1b^T + b1  (coalesced via W1T) ----------------
// 128 threads/block, 2 rows/block -> 384 blocks (1.5/CU)
#define P1R 2
__global__ __launch_bounds__(128) void p1_kernel(
    const float* __restrict__ z, const float* __restrict__ W1T,
    const float* __restrict__ b1, float* __restrict__ U, float* __restrict__ Vb) {
  __shared__ __align__(16) float zsh[P1R][H];
  const int t = threadIdx.x;
  const int rbase = blockIdx.x * P1R;
  if (t < P1R * (H / 4)) {
    const int r = t >> 5, c4 = t & 31;
    ((float4*)zsh[r])[c4] = ((const float4*)(z + (size_t)(rbase + r) * H))[c4];
  }
  __syncthreads();
  const int q = t & 31;            // k-quad (0..31)
  const int half = (t >> 5) & 1;   // 0 -> U, 1 -> Vb (intra-wave: two 512B runs/load)
  const int r = t >> 6;            // 0..1 (wave-uniform)
  const float4* __restrict__ wt = (const float4*)(W1T + (size_t)half * H * H) + q;
  float4 acc = {0.f, 0.f, 0.f, 0.f};
#pragma unroll 4                    // cap: full unroll spilled (round-2: VGPR=256, 43MB scratch)
  for (int m = 0; m < H; m += 4) {
    const float4 zq = *(const float4*)&zsh[r][m];   // wave-uniform broadcast
    const float4 w0 = wt[(size_t)(m + 0) * 32];
    const float4 w1 = wt[(size_t)(m + 1) * 32];
    const float4 w2 = wt[(size_t)(m + 2) * 32];
    const float4 w3 = wt[(size_t)(m + 3) * 32];
    acc.x = fmaf(w0.x, zq.x, acc.x); acc.y = fmaf(w0.y, zq.x, acc.y);
    acc.z = fmaf(w0.z, zq.x, acc.z); acc.w = fmaf(w0.w, zq.x, acc.w);
    acc.x = fmaf(w1.x, zq.y, acc.x); acc.y = fmaf(w1.y, zq.y, acc.y);
    acc.z = fmaf(w1.z, zq.y, acc.z); acc.w = fmaf(w1.w, zq.y, acc.w);
    acc.x = fmaf(w2.x, zq.z, acc.x); acc.y = fmaf(w2.y, zq.z, acc.y);
    acc.z = fmaf(w2.z, zq.z, acc.z); acc.w = fmaf(w2.w, zq.z, acc.w);
    acc.x = fmaf(w3.x, zq.w, acc.x); acc.y = fmaf(w3.y, zq.w, acc.y);
    acc.z = fmaf(w3.z, zq.w, acc.z); acc.w = fmaf(w3.w, zq.w, acc.w);
  }
  float4 bias = {0.f, 0.f, 0.f, 0.f};
  if (half) bias = ((const float4*)b1)[q];
  float* dst = half ? Vb : U;
  float4 outv = {acc.x + bias.x, acc.y + bias.y, acc.z + bias.z, acc.w + bias.w};
  *(float4*)&dst[(size_t)(rbase + r) * H + 4 * q] = outv;
}

// ---------------- p2: out[i,j] = sum_k relu(U[i,k]+Vb[j,k]) * w2[k] + b2 ----------------
// 32x32 tiles, 2x2 regs/thread, 576 blocks (2.25/CU), LDS 33.8KB (<=4 blocks/CU)
#define TI 32
#define TJ 32
#define LDSW (H + 4)  // rows shift 4 banks: uu broadcast, vv 2-way (free)
__global__ __launch_bounds__(256) void p2_kernel(
    const float* __restrict__ U, const float* __restrict__ Vb,
    const float* __restrict__ w2, const float* __restrict__ b2,
    float* __restrict__ out) {
  __shared__ __align__(16) float ush[TI * LDSW];
  __shared__ __align__(16) float vsh[TJ * LDSW];
  const int t = threadIdx.x;
  const int bi = (blockIdx.x / 24) * TI;
  const int bj = (blockIdx.x % 24) * TJ;
#pragma unroll
  for (int l = t; l < TI * (H / 4); l += 256) {
    const int r = l >> 5, c4 = l & 31;
    *(float4*)&ush[r * LDSW + c4 * 4] = ((const float4*)(U  + (size_t)(bi + r) * H))[c4];
    *(float4*)&vsh[r * LDSW + c4 * 4] = ((const float4*)(Vb + (size_t)(bj + r) * H))[c4];
  }
  __syncthreads();
  const int tx = t & 15, ty = t >> 4;
  float acc[2][2] = {};
#pragma unroll 8
  for (int k = 0; k < H; k += 4) {
    const float4 w = *(const float4*)(w2 + k);  // uniform -> scalar load
    float4 uu[2], vv[2];
#pragma unroll
    for (int r = 0; r < 2; ++r) uu[r] = *(const float4*)&ush[(ty + 16 * r) * LDSW + k];
#pragma unroll
    for (int r = 0; r < 2; ++r) vv[r] = *(const float4*)&vsh[(tx + 16 * r) * LDSW + k];
#pragma unroll
    for (int a = 0; a < 2; ++a)
#pragma unroll
      for (int b = 0; b < 2; ++b) {
        acc[a][b] = fmaf(fmaxf(uu[a].x + vv[b].x, 0.f), w.x, acc[a][b]);
        acc[a][b] = fmaf(fmaxf(uu[a].y + vv[b].y, 0.f), w.y, acc[a][b]);
        acc[a][b] = fmaf(fmaxf(uu[a].z + vv[b].z, 0.f), w.z, acc[a][b]);
        acc[a][b] = fmaf(fmaxf(uu[a].w + vv[b].w, 0.f), w.w, acc[a][b]);
      }
  }
  const float bb = b2[0];
#pragma unroll
  for (int a = 0; a < 2; ++a) {
    const int i = bi + ty + 16 * a;
#pragma unroll
    for (int b = 0; b < 2; ++b) {
      const int j = bj + tx + 16 * b;
      if (i != j) out[(size_t)i * NM1 + j - (j > i ? 1 : 0)] = acc[a][b] + bb;
    }
  }
}

extern "C" void kernel_launch(void* const* d_in, const int* in_sizes, int n_in,
                              void* d_out, int out_size, void* d_ws, size_t ws_size,
                              hipStream_t stream) {
  const float* z  = (const float*)d_in[0];
  const float* W1 = (const float*)d_in[1];
  const float* b1 = (const float*)d_in[2];
  const float* W2 = (const float*)d_in[3];
  const float* b2 = (const float*)d_in[4];
  float* U   = (float*)d_ws;
  float* Vb  = U + N * H;
  float* W1T = Vb + N * H;
  p0_transpose<<<32, 256, 0, stream>>>(W1, W1T);
  p1_kernel<<<N / P1R, 128, 0, stream>>>(z, W1T, b1, U, Vb);
  p2_kernel<<<(N / TI) * (N / TJ), 256, 0, stream>>>(U, Vb, W2, b2, (float*)d_out);
}

// Round 6
// 21.869 us; speedup vs baseline: 2.6783x; 1.3103x over previous
//
#include <hip/hip_runtime.h>

#define N 768
#define H 128
#define NM1 767

// ---------------- p1: U = z@W1a^T ; Vb = z@W1b^T + b1  (direct W1 read, no transpose) ----------------
// lane = output channel k; each lane streams its OWN contiguous 512B W1 half-row
// (L1 line reused 8x by consecutive m-quads). 4 z-rows per block -> 192 blocks.
#define P1R 4
__global__ __launch_bounds__(256) void p1_direct(
    const float* __restrict__ z, const float* __restrict__ W1,
    const float* __restrict__ b1, float* __restrict__ U, float* __restrict__ Vb) {
  __shared__ __align__(16) float zsh[P1R][H];
  const int t = threadIdx.x;
  const int rbase = blockIdx.x * P1R;
  if (t < P1R * (H / 4)) {
    const int r = t >> 5, c4 = t & 31;
    ((float4*)zsh[r])[c4] = ((const float4*)(z + (size_t)(rbase + r) * H))[c4];
  }
  __syncthreads();
  const int k = t & (H - 1);       // output channel (lanes consecutive -> coalesced stores)
  const int half = t >> 7;         // 0 -> U, 1 -> Vb (wave-uniform)
  const float* __restrict__ wrow = W1 + (size_t)k * (2 * H) + half * H;
  float a0 = 0.f, a1 = 0.f, a2 = 0.f, a3 = 0.f;
#pragma unroll 4                    // cap: full unroll spills (R2: VGPR=256, 43MB scratch)
  for (int m = 0; m < H; m += 4) {
    const float4 w  = *(const float4*)(wrow + m);       // per-lane own row, L1-resident
    const float4 z0 = *(const float4*)&zsh[0][m];       // wave-uniform broadcasts
    const float4 z1 = *(const float4*)&zsh[1][m];
    const float4 z2 = *(const float4*)&zsh[2][m];
    const float4 z3 = *(const float4*)&zsh[3][m];
    a0 = fmaf(w.x, z0.x, a0); a0 = fmaf(w.y, z0.y, a0);
    a0 = fmaf(w.z, z0.z, a0); a0 = fmaf(w.w, z0.w, a0);
    a1 = fmaf(w.x, z1.x, a1); a1 = fmaf(w.y, z1.y, a1);
    a1 = fmaf(w.z, z1.z, a1); a1 = fmaf(w.w, z1.w, a1);
    a2 = fmaf(w.x, z2.x, a2); a2 = fmaf(w.y, z2.y, a2);
    a2 = fmaf(w.z, z2.z, a2); a2 = fmaf(w.w, z2.w, a2);
    a3 = fmaf(w.x, z3.x, a3); a3 = fmaf(w.y, z3.y, a3);
    a3 = fmaf(w.z, z3.z, a3); a3 = fmaf(w.w, z3.w, a3);
  }
  const float bias = half ? b1[k] : 0.f;
  float* dst = half ? Vb : U;
  dst[(size_t)(rbase + 0) * H + k] = a0 + bias;
  dst[(size_t)(rbase + 1) * H + k] = a1 + bias;
  dst[(size_t)(rbase + 2) * H + k] = a2 + bias;
  dst[(size_t)(rbase + 3) * H + k] = a3 + bias;
}

// ---------------- p2: out[i,j] = sum_k relu(U[i,k]+Vb[j,k]) * w2[k] + b2 ----------------
// UNCHANGED from round 5 (clean A/B on node count).
#define TI 32
#define TJ 32
#define LDSW (H + 4)  // rows shift 4 banks: uu broadcast, vv 2-way (free)
__global__ __launch_bounds__(256) void p2_kernel(
    const float* __restrict__ U, const float* __restrict__ Vb,
    const float* __restrict__ w2, const float* __restrict__ b2,
    float* __restrict__ out) {
  __shared__ __align__(16) float ush[TI * LDSW];
  __shared__ __align__(16) float vsh[TJ * LDSW];
  const int t = threadIdx.x;
  const int bi = (blockIdx.x / 24) * TI;
  const int bj = (blockIdx.x % 24) * TJ;
#pragma unroll
  for (int l = t; l < TI * (H / 4); l += 256) {
    const int r = l >> 5, c4 = l & 31;
    *(float4*)&ush[r * LDSW + c4 * 4] = ((const float4*)(U  + (size_t)(bi + r) * H))[c4];
    *(float4*)&vsh[r * LDSW + c4 * 4] = ((const float4*)(Vb + (size_t)(bj + r) * H))[c4];
  }
  __syncthreads();
  const int tx = t & 15, ty = t >> 4;
  float acc[2][2] = {};
#pragma unroll 8
  for (int k = 0; k < H; k += 4) {
    const float4 w = *(const float4*)(w2 + k);  // uniform -> scalar load
    float4 uu[2], vv[2];
#pragma unroll
    for (int r = 0; r < 2; ++r) uu[r] = *(const float4*)&ush[(ty + 16 * r) * LDSW + k];
#pragma unroll
    for (int r = 0; r < 2; ++r) vv[r] = *(const float4*)&vsh[(tx + 16 * r) * LDSW + k];
#pragma unroll
    for (int a = 0; a < 2; ++a)
#pragma unroll
      for (int b = 0; b < 2; ++b) {
        acc[a][b] = fmaf(fmaxf(uu[a].x + vv[b].x, 0.f), w.x, acc[a][b]);
        acc[a][b] = fmaf(fmaxf(uu[a].y + vv[b].y, 0.f), w.y, acc[a][b]);
        acc[a][b] = fmaf(fmaxf(uu[a].z + vv[b].z, 0.f), w.z, acc[a][b]);
        acc[a][b] = fmaf(fmaxf(uu[a].w + vv[b].w, 0.f), w.w, acc[a][b]);
      }
  }
  const float bb = b2[0];
#pragma unroll
  for (int a = 0; a < 2; ++a) {
    const int i = bi + ty + 16 * a;
#pragma unroll
    for (int b = 0; b < 2; ++b) {
      const int j = bj + tx + 16 * b;
      if (i != j) out[(size_t)i * NM1 + j - (j > i ? 1 : 0)] = acc[a][b] + bb;
    }
  }
}

extern "C" void kernel_launch(void* const* d_in, const int* in_sizes, int n_in,
                              void* d_out, int out_size, void* d_ws, size_t ws_size,
                              hipStream_t stream) {
  const float* z  = (const float*)d_in[0];
  const float* W1 = (const float*)d_in[1];
  const float* b1 = (const float*)d_in[2];
  const float* W2 = (const float*)d_in[3];
  const float* b2 = (const float*)d_in[4];
  float* U  = (float*)d_ws;
  float* Vb = U + N * H;
  p1_direct<<<N / P1R, 256, 0, stream>>>(z, W1, b1, U, Vb);
  p2_kernel<<<(N / TI) * (N / TJ), 256, 0, stream>>>(U, Vb, W2, b2, (float*)d_out);
}